// Round 6
// baseline (94.194 us; speedup 1.0000x reference)
//
#include <hip/hip_runtime.h>
#include <math.h>

#define N 8
#define C 128
#define L 1024
#define K 100
#define TEMP 0.5f
#define EPS 1e-8f

#define PA 136   // halves pitch for a/b tiles (bytes 272 = 16*17: b128-aligned rows)
#define PD 132   // float pitch for D tile

typedef _Float16 v8h __attribute__((ext_vector_type(8)));
typedef float v4f __attribute__((ext_vector_type(4)));
typedef _Float16 h2 __attribute__((ext_vector_type(2)));

__device__ __forceinline__ float fd2(h2 a, h2 b, float acc) {
#if __has_builtin(__builtin_amdgcn_fdot2)
    return __builtin_amdgcn_fdot2(a, b, acc, false);
#else
    return acc + (float)a[0] * (float)b[0] + (float)a[1] * (float)b[1];
#endif
}

// One block per (n, t-tile of 128, l-tile of 128). 256 threads = 4 waves.
// Phase 1: stage c-tile -> a_lds[t][ch], z-tile -> b_lds[l][ch] (fp32->fp16).
// Phase 2: norms from staged tiles (K=C=128 entirely in-block).
// Phase 3: D[t][l] = sum_ch a*b via mfma 16x16x32 f16 (4 waves x 16 frags).
// Phase 4: D -> LDS (reusing a/b space), gather neg_inds, emit logits whose
//          idx falls in this block's l-range. Every (t,kk) written exactly once.
__global__ void __launch_bounds__(256, 2)
gemm_fused(const float* __restrict__ z, const float* __restrict__ c,
           const int* __restrict__ neg, float* __restrict__ out) {
    __shared__ __align__(16) char smem[69632];
    _Float16* a_lds = (_Float16*)smem;              // [128][PA] c-tile (t, ch)
    _Float16* b_lds = (_Float16*)(smem + 34816);    // [128][PA] z-tile (l, ch)
    float* d_lds = (float*)smem;                    // [128][PD] D (t, l), overlays a/b
    __shared__ float cn_s[128], tn_s[128];

    const int tid = threadIdx.x;
    const int lb = blockIdx.x;          // l-tile index (0..7)
    const int tb = blockIdx.y;          // t-tile index (0..7)
    const int n  = blockIdx.z;

    // ---- stage z tile: b_lds[l][ch] = (f16) z[n][ch][lb*128 + l]  (aligned float4)
    {
        const int ch = tid >> 1, hf = tid & 1;
        const float* src = z + ((size_t)(n * C + ch)) * L + lb * 128 + hf * 64;
        _Float16* dst = b_lds + ch;
#pragma unroll
        for (int j = 0; j < 16; j++) {
            float4 v = *(const float4*)(src + 4 * j);
            int cl = hf * 64 + 4 * j;
            dst[(size_t)(cl + 0) * PA] = (_Float16)v.x;
            dst[(size_t)(cl + 1) * PA] = (_Float16)v.y;
            dst[(size_t)(cl + 2) * PA] = (_Float16)v.z;
            dst[(size_t)(cl + 3) * PA] = (_Float16)v.w;
        }
    }
    // ---- stage c tile: a_lds[t][ch] = (f16) c[n][ch][tb*128 + t + 1]
    // (c rows are odd-strided -> scalar loads, but lanes run along t: coalesced)
    {
        const int ch2 = tid >> 7;           // 0..1
        const int tl  = tid & 127;          // 0..127
        const float* srcc = c + tb * 128 + 1 + tl;
        _Float16* dst = a_lds + (size_t)tl * PA;
#pragma unroll 8
        for (int k2 = 0; k2 < 64; k2++) {
            int ch = ch2 + 2 * k2;
            dst[ch] = (_Float16)srcc[(size_t)(n * C + ch) * (L + 1)];
        }
    }
    __syncthreads();

    // ---- norms from staged fp16 (fp32 accumulate)
    {
        const int x = tid >> 1, hf = tid & 1;
        const h2* pa = (const h2*)(a_lds + (size_t)x * PA + hf * 64);
        const h2* pb = (const h2*)(b_lds + (size_t)x * PA + hf * 64);
        float sa = 0.f, sb = 0.f;
#pragma unroll
        for (int j = 0; j < 32; j++) {
            sa = fd2(pa[j], pa[j], sa);
            sb = fd2(pb[j], pb[j], sb);
        }
        sa += __shfl_xor(sa, 1);
        sb += __shfl_xor(sb, 1);
        if (hf == 0) { cn_s[x] = sa; tn_s[x] = sb; }
    }

    // ---- MFMA: each wave computes a 64x64 quadrant of D
    const int wave = tid >> 6, lane = tid & 63;
    const int wt = wave >> 1, wl = wave & 1;
    const int m = lane & 15, kq = lane >> 4;
    v4f acc[4][4] = {};
#pragma unroll
    for (int ks = 0; ks < 4; ks++) {
        v8h aF[4], bF[4];
#pragma unroll
        for (int i = 0; i < 4; i++)
            aF[i] = *(const v8h*)(a_lds + (size_t)(wt * 64 + i * 16 + m) * PA + ks * 32 + kq * 8);
#pragma unroll
        for (int j = 0; j < 4; j++)
            bF[j] = *(const v8h*)(b_lds + (size_t)(wl * 64 + j * 16 + m) * PA + ks * 32 + kq * 8);
#pragma unroll
        for (int i = 0; i < 4; i++)
#pragma unroll
            for (int j = 0; j < 4; j++)
                acc[i][j] = __builtin_amdgcn_mfma_f32_16x16x32_f16(aF[i], bF[j], acc[i][j], 0, 0, 0);
    }
    __syncthreads();   // all a/b reads done before overlaying with D

    // ---- D -> LDS. C/D layout: col = lane&15, row = (lane>>4)*4 + reg
#pragma unroll
    for (int i = 0; i < 4; i++)
#pragma unroll
        for (int j = 0; j < 4; j++) {
            int row = wt * 64 + i * 16 + kq * 4;
            int col = wl * 64 + j * 16 + m;
#pragma unroll
            for (int r = 0; r < 4; r++)
                d_lds[(size_t)(row + r) * PD + col] = acc[i][j][r];
        }
    __syncthreads();

    // ---- gather epilogue: 2 threads per t (k-halves)
    {
        const int tl = tid >> 1, hf = tid & 1;
        const int tq = tb * 128 + tl;
        const size_t nt = (size_t)n * L + tq;
        const float cn = cn_s[tl];
        const float rcn = rsqrtf(fmaxf(cn, EPS * EPS));
        const int* nip = neg + nt * K;
        float* orow = out + nt * (K + 1);
        const int kbase = hf * 51;
        const int kcnt = 51 - hf;          // hf0: kk 0..50, hf1: kk 51..100
        for (int q0 = 0; q0 < kcnt; q0 += 8) {
            int idv[8];
#pragma unroll
            for (int e = 0; e < 8; e++) {
                int q = q0 + e, kk = kbase + q;
                idv[e] = (q < kcnt) ? ((kk == 0) ? tq : nip[kk - 1]) : -1;
            }
#pragma unroll
            for (int e = 0; e < 8; e++) {
                int idx = idv[e];
                if (idx >= 0 && (idx >> 7) == lb) {
                    int kk = kbase + q0 + e;
                    int ll = idx & 127;
                    float dot = d_lds[(size_t)tl * PD + ll];
                    float tn = tn_s[ll];
                    float logit = 2.0f * dot * rcn * rsqrtf(fmaxf(tn, EPS * EPS));
                    if (kk > 0 && (cn - 2.f * dot + tn) < 0.05f * cn) {
                        // near-equal: exact fp32 recheck (never taken on random data)
                        bool eq = true;
                        for (int q2 = 0; q2 < C; q2++)
                            eq = eq && (c[((size_t)(n * C + q2)) * (L + 1) + tq + 1] ==
                                        z[((size_t)(n * C + q2)) * L + idx]);
                        if (eq) logit = -INFINITY;
                    }
                    orow[kk] = logit;
                }
            }
        }
    }
}

extern "C" void kernel_launch(void* const* d_in, const int* in_sizes, int n_in,
                              void* d_out, int out_size, void* d_ws, size_t ws_size,
                              hipStream_t stream) {
    const float* z   = (const float*)d_in[0];   // (N, C, L)
    const float* c   = (const float*)d_in[1];   // (N, C, L+1)
    const int*   neg = (const int*)d_in[2];     // (N, L, K)
    float* out = (float*)d_out;                 // (N*L, K+1)
    (void)d_ws; (void)ws_size;

    gemm_fused<<<dim3(8, 8, N), 256, 0, stream>>>(z, c, neg, out);
}

// Round 7
// 92.116 us; speedup vs baseline: 1.0226x; 1.0226x over previous
//
#include <hip/hip_runtime.h>
#include <math.h>

#define N 8
#define C 128
#define L 1024
#define K 100
#define TEMP 0.5f
#define EPS 1e-8f
#define NT (N * L)

#define TQ 256      // l-rows per quarter slab
#define TT 32       // t's per block
#define HCAP 104    // per-(wave,t) compacted-hit capacity (worst case 101)

typedef _Float16 h2 __attribute__((ext_vector_type(2)));
typedef _Float16 v8h __attribute__((ext_vector_type(8)));

__device__ __forceinline__ float fd2(h2 a, h2 b, float acc) {
#if __has_builtin(__builtin_amdgcn_fdot2)
    return __builtin_amdgcn_fdot2(a, b, acc, false);
#else
    return acc + (float)a[0] * (float)b[0] + (float)a[1] * (float)b[1];
#endif
}

// quad_perm DPP cross-lane add: xor1 = 0xB1, xor2 = 0x4E
#if __has_builtin(__builtin_amdgcn_mov_dpp)
#define DPP_ADD(x, ctrl) ((x) + __int_as_float(__builtin_amdgcn_mov_dpp(__float_as_int(x), (ctrl), 0xF, 0xF, true)))
#else
#define DPP_ADD(x, ctrl) ((x) + __shfl_xor((x), ((ctrl) == 0xB1 ? 1 : 2)))
#endif

// Transpose+fp16-convert+fp32-row-norm partials (unchanged from R5).
__global__ void __launch_bounds__(512)
transpose_both(const float* __restrict__ z, const float* __restrict__ c,
               _Float16* __restrict__ z_h, _Float16* __restrict__ c_h,
               float* __restrict__ zp, float* __restrict__ cp) {
    __shared__ float tile[64][65];
    __shared__ float part[8][64];
    const int which = blockIdx.z >> 3;
    const int n = blockIdx.z & 7;
    const float* src = which ? c : z;
    _Float16* dst = which ? c_h : z_h;
    float* pdst = which ? cp : zp;
    const int slen = which ? (L + 1) : L;
    const int off = which;
    const int l0 = blockIdx.x * 64;
    const int c0 = blockIdx.y * 64;
    const int tx = threadIdx.x, ty = threadIdx.y;
#pragma unroll
    for (int i = 0; i < 8; i++) {
        int chn = c0 + ty + i * 8;
        tile[ty + i * 8][tx] = src[((size_t)(n * C + chn)) * slen + off + l0 + tx];
    }
    __syncthreads();
#pragma unroll
    for (int i = 0; i < 8; i++) {
        int l = l0 + ty + i * 8;
        dst[((size_t)n * L + l) * C + c0 + tx] = (_Float16)tile[tx][ty + i * 8];
    }
    float p = 0.f;
#pragma unroll
    for (int i = 0; i < 8; i++) { float v = tile[ty * 8 + i][tx]; p += v * v; }
    part[ty][tx] = p;
    __syncthreads();
    if (ty == 0) {
        float sm = 0.f;
#pragma unroll
        for (int i = 0; i < 8; i++) sm += part[i][tx];
        pdst[(((size_t)n << 10) + l0 + tx) * 2 + (c0 >> 6)] = sm;
    }
}

// One block per (n, quarter q, t-chunk of 32). Stage z-quarter in LDS
// (chunk-XOR-swizzled), compact each t's neg hits for this quarter via
// ballot+mbcnt, then dense LDS-gather dots (4 lanes/target, DPP reduce).
__global__ void __launch_bounds__(256, 2)
lds_gather(const _Float16* __restrict__ zh, const _Float16* __restrict__ chh,
           const int* __restrict__ neg,
           const float* __restrict__ zp, const float* __restrict__ cp,
           const float* __restrict__ z_orig, const float* __restrict__ c_orig,
           float* __restrict__ out) {
    __shared__ __align__(16) _Float16 zl[TQ * C];   // 64 KB, swizzled rows
    __shared__ __align__(16) _Float16 cl[TT * C];   // 8 KB
    __shared__ float zn[TQ];
    __shared__ float cns[TT];
    __shared__ unsigned short hits[4][8][HCAP];     // (kk<<8)|idx_local
    __shared__ int nh_sh[4][8];

    const int tid = threadIdx.x;
    const int q  = blockIdx.x;        // quarter 0..3
    const int tc = blockIdx.y;        // t-chunk 0..31
    const int n  = blockIdx.z;
    const int w = tid >> 6, lane = tid & 63;
    const int g = lane >> 2, s = lane & 3;

    // ---- stage z quarter: row r chunk j stored at phys chunk j^(r&15)
    {
        const uint4* src = (const uint4*)(zh + ((size_t)(n * L + q * TQ)) * C);
#pragma unroll
        for (int i = 0; i < 16; i++) {
            int flat = i * 256 + tid;               // 16B-chunk id
            int row = flat >> 4, chk = flat & 15;
            uint4 v = src[flat];
            *(uint4*)(zl + row * C + (((chk ^ (row & 15)) << 3))) = v;
        }
    }
    // ---- stage c tile (linear; later reads are quad-broadcast)
    {
        const uint4* src = (const uint4*)(chh + ((size_t)(n * L + tc * TT)) * C);
        uint4* dst = (uint4*)cl;
        dst[tid] = src[tid];
        dst[tid + 256] = src[tid + 256];
    }
    // ---- norms (fp32, from transpose kernel's partials)
    {
        const float2* zp2 = (const float2*)zp + (size_t)n * L + q * TQ;
        float2 v = zp2[tid];
        zn[tid] = v.x + v.y;
        if (tid < TT) {
            float2 u = ((const float2*)cp)[(size_t)n * L + tc * TT + tid];
            cns[tid] = u.x + u.y;
        }
    }
    // ---- scan+compact: per wave, 8 t's; all 64 lanes participate
    for (int i = 0; i < 8; i++) {
        int tt = w * 8 + i;
        int tg = tc * TT + tt;
        const int* ni = neg + ((size_t)n * L + tg) * K;
        int ia = (lane == 0) ? tg : ni[lane - 1];             // kk = lane (0..63)
        bool pa = (ia >> 8) == q;
        int ib = (lane < K - 63) ? ni[63 + lane] : -1;        // kk = 64+lane (<=100)
        bool pb = (lane < K - 63) && ((ib >> 8) == q);
        unsigned long long ba = __ballot(pa);
        unsigned long long bb = __ballot(pb);
        int posa = __builtin_amdgcn_mbcnt_hi((unsigned)(ba >> 32),
                   __builtin_amdgcn_mbcnt_lo((unsigned)ba, 0));
        int ca = __popcll(ba);
        int posb = ca + __builtin_amdgcn_mbcnt_hi((unsigned)(bb >> 32),
                   __builtin_amdgcn_mbcnt_lo((unsigned)bb, 0));
        if (pa) hits[w][i][posa] = (unsigned short)((lane << 8) | (ia & 255));
        if (pb) hits[w][i][posb] = (unsigned short)(((64 + lane) << 8) | (ib & 255));
        if (lane == 0) nh_sh[w][i] = ca + __popcll(bb);
    }
    __syncthreads();

    // ---- dense gather: 16 quads x 1 hit per iter, ~25 hits/t
    for (int i = 0; i < 8; i++) {
        const int tt = w * 8 + i;
        const int tg = tc * TT + tt;
        const size_t nt = (size_t)n * L + tg;
        v8h cf[4];
#pragma unroll
        for (int j = 0; j < 4; j++)
            cf[j] = *(const v8h*)(cl + tt * C + ((s + 4 * j) << 3));
        const float cn = cns[tt];
        const float rcn = rsqrtf(fmaxf(cn, EPS * EPS));
        const int nh = nh_sh[w][i];
        const unsigned short* hl = hits[w][i];
        float* orow = out + nt * (K + 1);
        for (int h0 = 0; h0 < nh; h0 += 16) {
            int slot = h0 + g;
            if (slot < nh) {
                int e = hl[slot];
                int kk = e >> 8, il = e & 255, key = il & 15;
                const _Float16* zr = zl + il * C;
                float d0 = 0.f, d1 = 0.f;
#pragma unroll
                for (int j = 0; j < 4; j++) {
                    v8h zv = *(const v8h*)(zr + (((s + 4 * j) ^ key) << 3));
                    const h2* cz = (const h2*)&cf[j];
                    const h2* zz = (const h2*)&zv;
                    d0 = fd2(cz[0], zz[0], d0);
                    d1 = fd2(cz[1], zz[1], d1);
                    d0 = fd2(cz[2], zz[2], d0);
                    d1 = fd2(cz[3], zz[3], d1);
                }
                float dot = d0 + d1;
                dot = DPP_ADD(dot, 0xB1);
                dot = DPP_ADD(dot, 0x4E);
                if (s == 0) {
                    float tn = zn[il];
                    float logit = 2.0f * dot * rcn * rsqrtf(fmaxf(tn, EPS * EPS));
                    if (kk > 0 && (cn - 2.f * dot + tn) < 0.05f * cn) {
                        // near-equal: exact fp32 recheck (never taken on random data)
                        int idx = (q << 8) | il;
                        bool eq = true;
                        for (int p = 0; p < C; p++)
                            eq = eq && (c_orig[((size_t)(n * C + p)) * (L + 1) + tg + 1] ==
                                        z_orig[((size_t)(n * C + p)) * L + idx]);
                        if (eq) logit = -INFINITY;
                    }
                    orow[kk] = logit;
                }
            }
        }
    }
}

extern "C" void kernel_launch(void* const* d_in, const int* in_sizes, int n_in,
                              void* d_out, int out_size, void* d_ws, size_t ws_size,
                              hipStream_t stream) {
    const float* z   = (const float*)d_in[0];   // (N, C, L)
    const float* c   = (const float*)d_in[1];   // (N, C, L+1)
    const int*   neg = (const int*)d_in[2];     // (N, L, K)
    float* out = (float*)d_out;                 // (N*L, K+1)

    _Float16* z_h = (_Float16*)d_ws;            // (N, L, C) fp16, 2 MB
    _Float16* c_h = z_h + (size_t)NT * C;       // (N, L, C) fp16, 2 MB
    float* zp = (float*)(c_h + (size_t)NT * C); // (N*L, 2) fp32 norm partials
    float* cp = zp + (size_t)NT * 2;            // (N*L, 2) fp32 norm partials

    transpose_both<<<dim3(L / 64, C / 64, 16), dim3(64, 8), 0, stream>>>(z, c, z_h, c_h, zp, cp);
    lds_gather<<<dim3(4, L / TT, N), 256, 0, stream>>>(z_h, c_h, neg, zp, cp, z, c, out);
}

// Round 8
// 81.297 us; speedup vs baseline: 1.1586x; 1.1331x over previous
//
#include <hip/hip_runtime.h>
#include <math.h>

#define N 8
#define C 128
#define L 1024
#define K 100
#define TEMP 0.5f
#define EPS 1e-8f
#define NT (N * L)

typedef _Float16 h2 __attribute__((ext_vector_type(2)));
typedef _Float16 v8h __attribute__((ext_vector_type(8)));

__device__ __forceinline__ float fd2(h2 a, h2 b, float acc) {
#if __has_builtin(__builtin_amdgcn_fdot2)
    return __builtin_amdgcn_fdot2(a, b, acc, false);
#else
    return acc + (float)a[0] * (float)b[0] + (float)a[1] * (float)b[1];
#endif
}

// quad_perm DPP cross-lane add: xor1 = 0xB1, xor2 = 0x4E
#if __has_builtin(__builtin_amdgcn_mov_dpp)
#define DPP_ADD(x, ctrl) ((x) + __int_as_float(__builtin_amdgcn_mov_dpp(__float_as_int(x), (ctrl), 0xF, 0xF, true)))
#else
#define DPP_ADD(x, ctrl) ((x) + __shfl_xor((x), ((ctrl) == 0xB1 ? 1 : 2)))
#endif

// Fused transpose + full-row-norm + normalize + fp16 store.
// Block: 256 thr, covers ALL 128 channels x 32 l's -> norm computed in-block.
//   dst[n][l][ch] = (f16)( src[n][ch][off+l] * scale(l) )
//   scale = (which? 2 : 1) / max(||row||, EPS)   (TEMP folded into c)
// grid: (32 l-chunks, 2 which, 8 n)
__global__ void __launch_bounds__(256)
norm_transpose(const float* __restrict__ z, const float* __restrict__ c,
               _Float16* __restrict__ z_h, _Float16* __restrict__ c_h) {
    __shared__ float tile[C][33];
    __shared__ float part[8][32];
    __shared__ float scale_s[32];
    const int chunk = blockIdx.x;
    const int which = blockIdx.y;
    const int n = blockIdx.z;
    const float* src = which ? c : z;
    _Float16* dst = which ? c_h : z_h;
    const int slen = which ? (L + 1) : L;
    const int off = which;          // c: skip col 0
    const int tid = threadIdx.x;
    const int tx = tid & 31;        // l within chunk
    const int ty = tid >> 5;        // 0..7

#pragma unroll
    for (int i = 0; i < 16; i++) {
        int ch = ty + 8 * i;
        tile[ch][tx] = src[((size_t)(n * C + ch)) * slen + off + chunk * 32 + tx];
    }
    __syncthreads();
    float sm = 0.f;
#pragma unroll
    for (int i = 0; i < 16; i++) { float v = tile[ty * 16 + i][tx]; sm += v * v; }
    part[ty][tx] = sm;
    __syncthreads();
    if (ty == 0) {
        float s2 = 0.f;
#pragma unroll
        for (int i = 0; i < 8; i++) s2 += part[i][tx];
        float nrm = fmaxf(sqrtf(s2), EPS);
        scale_s[tx] = (which ? 2.0f : 1.0f) / nrm;
    }
    __syncthreads();
    const int ch = tid & 127;
    const int lq = tid >> 7;        // 0..1
#pragma unroll
    for (int j = 0; j < 16; j++) {
        int l = lq + 2 * j;
        dst[((size_t)(n * L + chunk * 32 + l)) * C + ch] =
            (_Float16)(tile[ch][l] * scale_s[l]);
    }
}

// 2 waves per (n,t): wave0 -> kk 0..50, wave1 -> kk 51..100.
// 4 lanes (quad) per target, 16 targets/iter, 4 iters, rows prefetched 1 ahead.
// logit = dot(c', z') directly (rows pre-normalized, TEMP folded in).
__global__ void __launch_bounds__(256)
ssl2(const _Float16* __restrict__ zh, const _Float16* __restrict__ chh,
     const int* __restrict__ neg,
     const float* __restrict__ z_orig, const float* __restrict__ c_orig,
     float* __restrict__ out) {
    const int tid  = threadIdx.x;
    const int lane = tid & 63;
    const int g    = lane >> 2;          // quad 0..15
    const int s    = lane & 3;           // slice
    const int h    = (tid >> 6) & 1;     // k-half
    const int nt   = blockIdx.x * 2 + (tid >> 7);
    const int n    = nt >> 10;
    const int t    = nt & (L - 1);

    const v8h* crow = (const v8h*)(chh + (size_t)nt * C);
    v8h cf[4];
#pragma unroll
    for (int j = 0; j < 4; j++) cf[j] = crow[s + 4 * j];

    const int* ni = neg + (size_t)nt * K;
    const _Float16* zbase = zh + (((size_t)n) << 10) * C;
    const int base = h * 51;
    const int kmax = h ? 101 : 51;

    int idxs[4];
#pragma unroll
    for (int i = 0; i < 4; i++) {
        int kk = base + i * 16 + g;
        idxs[i] = (kk == 0) ? t : ((kk < kmax) ? ni[kk - 1] : 0);
    }

    v8h rows[4][4];
    {
        const v8h* zr = (const v8h*)(zbase + (size_t)idxs[0] * C);
#pragma unroll
        for (int j = 0; j < 4; j++) rows[0][j] = zr[s + 4 * j];
    }
#pragma unroll
    for (int i = 0; i < 4; i++) {
        if (i + 1 < 4) {
            const v8h* zr = (const v8h*)(zbase + (size_t)idxs[i + 1] * C);
#pragma unroll
            for (int j = 0; j < 4; j++) rows[i + 1][j] = zr[s + 4 * j];
        }
        float d0 = 0.f, d1 = 0.f;
#pragma unroll
        for (int j = 0; j < 4; j++) {
            const h2* cz = (const h2*)&cf[j];
            const h2* zz = (const h2*)&rows[i][j];
            d0 = fd2(cz[0], zz[0], d0);
            d1 = fd2(cz[1], zz[1], d1);
            d0 = fd2(cz[2], zz[2], d0);
            d1 = fd2(cz[3], zz[3], d1);
        }
        float dot = d0 + d1;
        dot = DPP_ADD(dot, 0xB1);
        dot = DPP_ADD(dot, 0x4E);

        int kk = base + i * 16 + g;
        if (s == 0 && kk < kmax) {
            float logit = dot;
            if (kk > 0 && dot > 1.9f) {
                // only bit-equal rows can land here (dot ~ 2.0); exact recheck
                bool eq = true;
                for (int q = 0; q < C; q++)
                    eq = eq && (c_orig[((size_t)(n * C + q)) * (L + 1) + t + 1] ==
                                z_orig[((size_t)(n * C + q)) * L + idxs[i]]);
                if (eq) logit = -INFINITY;
            }
            out[(size_t)nt * (K + 1) + kk] = logit;
        }
    }
}

extern "C" void kernel_launch(void* const* d_in, const int* in_sizes, int n_in,
                              void* d_out, int out_size, void* d_ws, size_t ws_size,
                              hipStream_t stream) {
    const float* z   = (const float*)d_in[0];   // (N, C, L)
    const float* c   = (const float*)d_in[1];   // (N, C, L+1)
    const int*   neg = (const int*)d_in[2];     // (N, L, K)
    float* out = (float*)d_out;                 // (N*L, K+1)

    _Float16* z_h = (_Float16*)d_ws;            // (N, L, C) normalized fp16, 2 MB
    _Float16* c_h = z_h + (size_t)NT * C;       // (N, L, C) normalized fp16 (x2/TEMP)

    norm_transpose<<<dim3(32, 2, N), 256, 0, stream>>>(z, c, z_h, c_h);
    ssl2<<<dim3(NT / 2), 256, 0, stream>>>(z_h, c_h, neg, z, c, out);
}